// Round 2
// baseline (162.294 us; speedup 1.0000x reference)
//
#include <hip/hip_runtime.h>
#include <math.h>

#define NROWS 8192
#define DIM 512
#define INV_T 20.0f
#define LOG_NEG_W 0.69314718055994531f

typedef __attribute__((ext_vector_type(4))) float f32x4;
typedef __attribute__((ext_vector_type(8))) __bf16 bf16x8;
typedef __attribute__((ext_vector_type(4))) __bf16 bf16x4;

__device__ __forceinline__ void gload_lds16(const void* g, void* l) {
    __builtin_amdgcn_global_load_lds(
        (const __attribute__((address_space(1))) unsigned int*)g,
        (__attribute__((address_space(3))) unsigned int*)l, 16, 0, 0);
}

__device__ __forceinline__ void block_bar() {
    asm volatile("" ::: "memory");
    __builtin_amdgcn_s_barrier();
    asm volatile("" ::: "memory");
}

__device__ __forceinline__ float dot4(float4 a, float4 b) {
    return a.x * b.x + a.y * b.y + a.z * b.z + a.w * b.w;
}

__device__ __forceinline__ bf16x4 to_bf4(float4 v, float sc) {
    bf16x4 r;
    r.x = (__bf16)(v.x * sc);
    r.y = (__bf16)(v.y * sc);
    r.z = (__bf16)(v.z * sc);
    r.w = (__bf16)(v.w * sc);
    return r;
}

// One wave per row: normalize a and s to bf16, compute exact fp32 diag,
// column log-weights, and zero the row-sum accumulator.
__global__ __launch_bounds__(256) void norm_kernel(
    const float* __restrict__ A, const float* __restrict__ S,
    const int* __restrict__ labels, __bf16* __restrict__ aB,
    __bf16* __restrict__ sB, float* __restrict__ diag,
    float* __restrict__ logw, float* __restrict__ lsum) {
    const int wave = threadIdx.x >> 6, lane = threadIdx.x & 63;
    const int row = blockIdx.x * 4 + wave;
    const float4* a4 = (const float4*)(A + (size_t)row * DIM);
    const float4* s4 = (const float4*)(S + (size_t)row * DIM);
    float4 a0 = a4[lane], a1 = a4[lane + 64];
    float4 s0 = s4[lane], s1 = s4[lane + 64];
    float saa = dot4(a0, a0) + dot4(a1, a1);
    float sss = dot4(s0, s0) + dot4(s1, s1);
    float sas = dot4(a0, s0) + dot4(a1, s1);
    for (int m = 1; m < 64; m <<= 1) {
        saa += __shfl_xor(saa, m);
        sss += __shfl_xor(sss, m);
        sas += __shfl_xor(sas, m);
    }
    const float ra = rsqrtf(saa), rs = rsqrtf(sss);
    __bf16* arow = aB + (size_t)row * DIM;
    __bf16* srow = sB + (size_t)row * DIM;
    *(bf16x4*)(arow + lane * 4)       = to_bf4(a0, ra);
    *(bf16x4*)(arow + 256 + lane * 4) = to_bf4(a1, ra);
    *(bf16x4*)(srow + lane * 4)       = to_bf4(s0, rs);
    *(bf16x4*)(srow + 256 + lane * 4) = to_bf4(s1, rs);
    if (lane == 0) {
        diag[row] = sas * ra * rs * INV_T;
        logw[row] = (labels[row] == 0) ? LOG_NEG_W : 0.0f;
        lsum[row] = 0.0f;
    }
}

// ---------------------------------------------------------------------------
// 256x256 8-phase fused GEMM + exp + row-sum.
// 8 waves (2M x 4N), BK=64, 2 K-tiles per 8 phases, 128 KiB LDS dbuf.
// Quarter-tile (8 KB) staging; counted vmcnt (10/8 steady state); XOR bank
// swizzle (slot ^= row&7) applied on BOTH global source and ds_read.
// ---------------------------------------------------------------------------
#define BM 256
#define BN 256
#define BK 64

__global__ __launch_bounds__(512, 2) void lse_gemm(
    const __bf16* __restrict__ Abf, const __bf16* __restrict__ Bbf,
    const float* __restrict__ logw, float* __restrict__ lsum) {
    __shared__ __align__(16) char lds[131072];

    const int nbn = NROWS / BN;  // 32
    const int rt = blockIdx.x / nbn, ct = blockIdx.x % nbn;
    const int row0 = rt * BM, col0 = ct * BN;
    const int tid = threadIdx.x;
    const int wid = tid >> 6, lane = tid & 63;
    const int wm = wid >> 2, wn = wid & 3;  // 2 x 4 wave grid

    // staging coords: thread t fills physical 16B slot (t&7) of row (t>>3)
    // of an 8KB quarter; it must fetch the data of logical slot (t&7)^(row&7)
    // (involution) so that swizzled ds_reads see linear data.
    const int sr = tid >> 3;              // row within quarter (0..63)
    const int ss = (tid & 7) ^ (sr & 7);  // logical slot fetched
    const int sdst = wid << 10;           // wave-uniform LDS dest offset

    const int fr = lane & 15;
    const int grp = lane >> 4;

    f32x4 acc[8][4] = {};
    bf16x8 a[4][2], b[4][2];

    // LDS map: buf d (0/1) at d*65536; A quarters at +qi*8192, B at +32768+qi*8192
    auto ldsAq = [&](int d, int qi) -> char* { return (char*)lds + d * 65536 + qi * 8192; };
    auto ldsBq = [&](int d, int qi) -> char* { return (char*)lds + d * 65536 + 32768 + qi * 8192; };

    auto stageA = [&](int d, int qi, int kt) {
        const __bf16* src = Abf + (size_t)(row0 + qi * 64 + sr) * DIM + kt * 64 + ss * 8;
        gload_lds16(src, ldsAq(d, qi) + sdst);
    };
    auto stageB = [&](int d, int qi, int kt) {
        const __bf16* src = Bbf + (size_t)(col0 + qi * 64 + sr) * DIM + kt * 64 + ss * 8;
        gload_lds16(src, ldsBq(d, qi) + sdst);
    };

    // fragment reads (swizzled): row rq, 16B slot s -> slot s^(rq&7)
    auto readA = [&](int d, int mq, int m, int ks) -> bf16x8 {
        const int rq = m * 16 + fr;
        const int off = rq * 128 + (((grp + ks * 4) ^ (rq & 7)) << 4);
        return *(const bf16x8*)(ldsAq(d, wm * 2 + mq) + off);
    };
    auto readB = [&](int d, int n, int ks) -> bf16x8 {
        const int rq = n * 16 + fr;
        const int off = rq * 128 + (((grp + ks * 4) ^ (rq & 7)) << 4);
        return *(const bf16x8*)(ldsBq(d, wn) + off);
    };

    // ---- prologue: T0 fully (8 quarters -> buf0), T1 partial (6 -> buf1)
    stageA(0, 0, 0); stageA(0, 1, 0); stageA(0, 2, 0); stageA(0, 3, 0);
    stageB(0, 0, 0); stageB(0, 1, 0); stageB(0, 2, 0); stageB(0, 3, 0);
    stageA(1, 0, 1); stageA(1, 2, 1);
    stageB(1, 0, 1); stageB(1, 1, 1); stageB(1, 2, 1); stageB(1, 3, 1);
    asm volatile("s_waitcnt vmcnt(6)" ::: "memory");  // T0 complete
    block_bar();

#pragma unroll 2
    for (int T = 0; T < 8; ++T) {
        const int cur = T & 1, nxt = cur ^ 1;

        // ---- phase 0: read A[m0-3] + B[n0-1]; stage A q1,q3 of T+1
#pragma unroll
        for (int m = 0; m < 4; ++m) {
            a[m][0] = readA(cur, 0, m, 0);
            a[m][1] = readA(cur, 0, m, 1);
        }
#pragma unroll
        for (int n = 0; n < 2; ++n) {
            b[n][0] = readB(cur, n, 0);
            b[n][1] = readB(cur, n, 1);
        }
        if (T + 1 < 8) { stageA(nxt, 1, T + 1); stageA(nxt, 3, T + 1); }
        block_bar();
        __builtin_amdgcn_s_setprio(1);
#pragma unroll
        for (int m = 0; m < 4; ++m)
#pragma unroll
            for (int n = 0; n < 2; ++n) {
                acc[m][n] = __builtin_amdgcn_mfma_f32_16x16x32_bf16(a[m][0], b[n][0], acc[m][n], 0, 0, 0);
                acc[m][n] = __builtin_amdgcn_mfma_f32_16x16x32_bf16(a[m][1], b[n][1], acc[m][n], 0, 0, 0);
            }
        __builtin_amdgcn_s_setprio(0);
        block_bar();

        // ---- phase 1: read B[n2-3]; stage A q0,q2 of T+2; vmcnt guards A q1,q3(T)
#pragma unroll
        for (int n = 2; n < 4; ++n) {
            b[n][0] = readB(cur, n, 0);
            b[n][1] = readB(cur, n, 1);
        }
        if (T + 2 < 8) {
            stageA(cur, 0, T + 2); stageA(cur, 2, T + 2);
            asm volatile("s_waitcnt vmcnt(10)" ::: "memory");
        } else if (T == 6) {
            asm volatile("s_waitcnt vmcnt(8)" ::: "memory");
        } else {
            asm volatile("s_waitcnt vmcnt(0)" ::: "memory");
        }
        block_bar();
        __builtin_amdgcn_s_setprio(1);
#pragma unroll
        for (int m = 0; m < 4; ++m)
#pragma unroll
            for (int n = 2; n < 4; ++n) {
                acc[m][n] = __builtin_amdgcn_mfma_f32_16x16x32_bf16(a[m][0], b[n][0], acc[m][n], 0, 0, 0);
                acc[m][n] = __builtin_amdgcn_mfma_f32_16x16x32_bf16(a[m][1], b[n][1], acc[m][n], 0, 0, 0);
            }
        __builtin_amdgcn_s_setprio(0);
        block_bar();

        // ---- phase 2: read A[m4-7] (reuse regs); stage B q0,q1 of T+2
#pragma unroll
        for (int m = 0; m < 4; ++m) {
            a[m][0] = readA(cur, 1, m, 0);
            a[m][1] = readA(cur, 1, m, 1);
        }
        if (T + 2 < 8) { stageB(cur, 0, T + 2); stageB(cur, 1, T + 2); }
        block_bar();
        __builtin_amdgcn_s_setprio(1);
#pragma unroll
        for (int m = 0; m < 4; ++m)
#pragma unroll
            for (int n = 2; n < 4; ++n) {
                acc[m + 4][n] = __builtin_amdgcn_mfma_f32_16x16x32_bf16(a[m][0], b[n][0], acc[m + 4][n], 0, 0, 0);
                acc[m + 4][n] = __builtin_amdgcn_mfma_f32_16x16x32_bf16(a[m][1], b[n][1], acc[m + 4][n], 0, 0, 0);
            }
        __builtin_amdgcn_s_setprio(0);
        block_bar();

        // ---- phase 3: stage B q2,q3 of T+2; vmcnt guards all of T+1
        if (T + 2 < 8) {
            stageB(cur, 2, T + 2); stageB(cur, 3, T + 2);
            asm volatile("s_waitcnt vmcnt(8)" ::: "memory");
        } else if (T == 6) {
            asm volatile("s_waitcnt vmcnt(2)" ::: "memory");
        }
        block_bar();
        __builtin_amdgcn_s_setprio(1);
#pragma unroll
        for (int m = 0; m < 4; ++m)
#pragma unroll
            for (int n = 0; n < 2; ++n) {
                acc[m + 4][n] = __builtin_amdgcn_mfma_f32_16x16x32_bf16(a[m][0], b[n][0], acc[m + 4][n], 0, 0, 0);
                acc[m + 4][n] = __builtin_amdgcn_mfma_f32_16x16x32_bf16(a[m][1], b[n][1], acc[m + 4][n], 0, 0, 0);
            }
        __builtin_amdgcn_s_setprio(0);
        block_bar();
    }

    // ---- epilogue: logits -> exp -> row sums -> atomicAdd
    // C/D layout: col = lane&15, row = (lane>>4)*4 + j
    float lw[4];
    int gc[4];
#pragma unroll
    for (int n = 0; n < 4; ++n) {
        gc[n] = col0 + wn * 64 + n * 16 + fr;
        lw[n] = logw[gc[n]];
    }
    const int rgrp = grp * 4;
#pragma unroll
    for (int m = 0; m < 8; ++m) {
        const int grbase = row0 + wm * 128 + m * 16 + rgrp;
        float rsum[4] = {0.f, 0.f, 0.f, 0.f};
#pragma unroll
        for (int n = 0; n < 4; ++n) {
#pragma unroll
            for (int j = 0; j < 4; ++j) {
                const float logit = acc[m][n][j] * INV_T +
                                    ((gc[n] == grbase + j) ? 0.0f : lw[n]);
                rsum[j] += __expf(logit);
            }
        }
#pragma unroll
        for (int j = 0; j < 4; ++j) {
            float v = rsum[j];
            v += __shfl_xor(v, 1);
            v += __shfl_xor(v, 2);
            v += __shfl_xor(v, 4);
            v += __shfl_xor(v, 8);
            if (fr == 0) atomicAdd(&lsum[grbase + j], v);
        }
    }
}

// Single block: final scalar reduction.
__global__ __launch_bounds__(256) void finalize_kernel(
    const float* __restrict__ lsum, const float* __restrict__ diag,
    const int* __restrict__ labels, float* __restrict__ out) {
    const int tid = threadIdx.x;
    float sl = 0.f, sd = 0.f, mx = -1e9f;
    int np_ = 0, nn_ = 0;
    for (int i = tid; i < NROWS; i += 256) {
        const float dg = diag[i];
        if (labels[i] == 1) {
            sl += logf(lsum[i]) - dg;
            sd += dg;
            np_++;
        } else {
            nn_++;
            mx = fmaxf(mx, dg);
        }
    }
    for (int m = 1; m < 64; m <<= 1) {
        sl += __shfl_xor(sl, m);
        sd += __shfl_xor(sd, m);
        mx = fmaxf(mx, __shfl_xor(mx, m));
        np_ += __shfl_xor(np_, m);
        nn_ += __shfl_xor(nn_, m);
    }
    __shared__ float rsl[4], rsd[4], rmx[4];
    __shared__ int rnp[4], rnn[4];
    const int wave = tid >> 6, lane = tid & 63;
    if (lane == 0) {
        rsl[wave] = sl; rsd[wave] = sd; rmx[wave] = mx;
        rnp[wave] = np_; rnn[wave] = nn_;
    }
    __syncthreads();
    if (tid == 0) {
        float SL = 0.f, SD = 0.f, MX = -1e9f;
        int NP = 0, NN = 0;
        for (int w = 0; w < 4; w++) {
            SL += rsl[w]; SD += rsd[w]; MX = fmaxf(MX, rmx[w]);
            NP += rnp[w]; NN += rnn[w];
        }
        const float infonce = SL / (float)NP;
        const float meanpos = SD / (float)NP;
        float pen = fmaxf(MX - meanpos + 0.2f, 0.0f);
        if (NN == 0) pen = 0.0f;
        out[0] = infonce + pen;
    }
}

extern "C" void kernel_launch(void* const* d_in, const int* in_sizes, int n_in,
                              void* d_out, int out_size, void* d_ws, size_t ws_size,
                              hipStream_t stream) {
    const float* A = (const float*)d_in[0];
    const float* S = (const float*)d_in[1];
    const int* labels = (const int*)d_in[2];
    float* out = (float*)d_out;

    char* ws = (char*)d_ws;
    __bf16* aB = (__bf16*)ws;                              // 8 MB
    __bf16* sB = (__bf16*)(ws + (size_t)NROWS * DIM * 2);  // 8 MB
    char* p = ws + (size_t)NROWS * DIM * 4;
    float* diag = (float*)p;                // 32 KB
    float* logw = (float*)(p + 32768);      // 32 KB
    float* lsum = (float*)(p + 65536);      // 32 KB

    norm_kernel<<<NROWS / 4, 256, 0, stream>>>(A, S, labels, aB, sB, diag, logw, lsum);
    lse_gemm<<<(NROWS / BM) * (NROWS / BN), 512, 0, stream>>>(aB, sB, logw, lsum);
    finalize_kernel<<<1, 256, 0, stream>>>(lsum, diag, labels, out);
}

// Round 3
// 132.067 us; speedup vs baseline: 1.2289x; 1.2289x over previous
//
#include <hip/hip_runtime.h>
#include <math.h>

#define NROWS 8192
#define DIM 512
#define INV_T 20.0f
#define LOG_NEG_W 0.69314718055994531f
#define QS 500.0f
#define DEQ (INV_T / (QS * QS))

typedef __attribute__((ext_vector_type(4))) int i32x4;

__device__ __forceinline__ void gload_lds16(const void* g, void* l) {
    __builtin_amdgcn_global_load_lds(
        (const __attribute__((address_space(1))) unsigned int*)g,
        (__attribute__((address_space(3))) unsigned int*)l, 16, 0, 0);
}

__device__ __forceinline__ void block_bar() {
    asm volatile("" ::: "memory");
    __builtin_amdgcn_s_barrier();
    asm volatile("" ::: "memory");
}

__device__ __forceinline__ float dot4(float4 a, float4 b) {
    return a.x * b.x + a.y * b.y + a.z * b.z + a.w * b.w;
}

__device__ __forceinline__ int q4(float4 v, float s) {
    int b0 = __float2int_rn(fminf(fmaxf(v.x * s, -127.f), 127.f)) & 255;
    int b1 = __float2int_rn(fminf(fmaxf(v.y * s, -127.f), 127.f)) & 255;
    int b2 = __float2int_rn(fminf(fmaxf(v.z * s, -127.f), 127.f)) & 255;
    int b3 = __float2int_rn(fminf(fmaxf(v.w * s, -127.f), 127.f)) & 255;
    return b0 | (b1 << 8) | (b2 << 16) | (b3 << 24);
}

// One wave per row: L2-normalize, quantize to i8 (scale QS), exact fp32 diag,
// column log-weights, zero row-sum accumulator.
__global__ __launch_bounds__(256) void norm_kernel(
    const float* __restrict__ A, const float* __restrict__ S,
    const int* __restrict__ labels, signed char* __restrict__ aQ,
    signed char* __restrict__ sQ, float* __restrict__ diag,
    float* __restrict__ logw, float* __restrict__ lsum) {
    const int wave = threadIdx.x >> 6, lane = threadIdx.x & 63;
    const int row = blockIdx.x * 4 + wave;
    const float4* a4 = (const float4*)(A + (size_t)row * DIM);
    const float4* s4 = (const float4*)(S + (size_t)row * DIM);
    float4 a0 = a4[lane], a1 = a4[lane + 64];
    float4 s0 = s4[lane], s1 = s4[lane + 64];
    float saa = dot4(a0, a0) + dot4(a1, a1);
    float sss = dot4(s0, s0) + dot4(s1, s1);
    float sas = dot4(a0, s0) + dot4(a1, s1);
    for (int m = 1; m < 64; m <<= 1) {
        saa += __shfl_xor(saa, m);
        sss += __shfl_xor(sss, m);
        sas += __shfl_xor(sas, m);
    }
    const float ra = rsqrtf(saa) * QS, rs = rsqrtf(sss) * QS;
    signed char* arow = aQ + (size_t)row * DIM;
    signed char* srow = sQ + (size_t)row * DIM;
    *(int*)(arow + lane * 4)       = q4(a0, ra);
    *(int*)(arow + 256 + lane * 4) = q4(a1, ra);
    *(int*)(srow + lane * 4)       = q4(s0, rs);
    *(int*)(srow + 256 + lane * 4) = q4(s1, rs);
    if (lane == 0) {
        diag[row] = sas * rsqrtf(saa) * rsqrtf(sss) * INV_T;
        logw[row] = (labels[row] == 0) ? LOG_NEG_W : 0.0f;
        lsum[row] = 0.0f;
    }
}

// ---------------------------------------------------------------------------
// 128x128 i8 fused GEMM + exp + row-sum. 4 waves (2x2), BK=64 (64 B rows),
// LDS double-buffer (32 KB), counted vmcnt(4) prefetch (never drains mid-loop),
// both-sides XOR slot swizzle (slot ^= (row>>1)&3) -> 2-way conflicts (free),
// 2D-quadrant XCD swizzle for L2 locality.
// ---------------------------------------------------------------------------
#define BM 128
#define BN 128

__global__ __launch_bounds__(256) void lse_gemm(
    const signed char* __restrict__ Aq, const signed char* __restrict__ Bq,
    const float* __restrict__ logw, float* __restrict__ lsum) {
    __shared__ __align__(16) char ldsA[2][BM * 64];  // 16 KB
    __shared__ __align__(16) char ldsB[2][BN * 64];  // 16 KB

    // XCD quadrant swizzle: 8 XCDs -> 4x2 quadrant grid of 16rt x 32ct
    const int bid = blockIdx.x;
    const int xcd = bid & 7, idx = bid >> 3;
    const int rt = (xcd & 3) * 16 + (idx >> 5);
    const int ct = (xcd >> 2) * 32 + (idx & 31);
    const int row0 = rt * BM, col0 = ct * BN;

    const int tid = threadIdx.x;
    const int wave = tid >> 6, lane = tid & 63;
    const int wm = wave >> 1, wn = wave & 1;
    const int fr = lane & 15, grp = lane >> 4;

    // staging: round r covers rows r*64 + (tid>>2); thread fills physical slot
    // (tid&3) of its row; fetches logical slot (tid&3)^((srow>>1)&3) so that
    // swizzled ds_reads see linear data (involution; row0 multiples drop out).
    const int srow = tid >> 2;
    const int sl = (tid & 3) ^ ((srow >> 1) & 3);
    const int sdst = wave << 10;  // wave-uniform LDS dest offset

    const size_t abase = (size_t)(row0 + srow) * DIM + sl * 16;
    const size_t bbase = (size_t)(col0 + srow) * DIM + sl * 16;

    i32x4 acc[4][4] = {};

    // fragment read swizzle: row m*16+fr -> phys slot grp ^ ((fr>>1)&3)
    const int pslot = (grp ^ ((fr >> 1) & 3)) << 4;

#define STAGE(buf, it)                                                        \
    do {                                                                      \
        gload_lds16(Aq + abase + (it) * 64,             ldsA[buf] + sdst);    \
        gload_lds16(Aq + abase + 64 * DIM + (it) * 64,  ldsA[buf] + 4096 + sdst); \
        gload_lds16(Bq + bbase + (it) * 64,             ldsB[buf] + sdst);    \
        gload_lds16(Bq + bbase + 64 * DIM + (it) * 64,  ldsB[buf] + 4096 + sdst); \
    } while (0)

    STAGE(0, 0);
#pragma unroll
    for (int it = 0; it < 8; ++it) {
        const int cur = it & 1;
        if (it < 7) {
            STAGE(cur ^ 1, it + 1);
            asm volatile("s_waitcnt vmcnt(4)" ::: "memory");
        } else {
            asm volatile("s_waitcnt vmcnt(0)" ::: "memory");
        }
        block_bar();  // all waves' cur tile staged

        i32x4 a[4], b[4];
#pragma unroll
        for (int m = 0; m < 4; ++m)
            a[m] = *(const i32x4*)&ldsA[cur][(wm * 64 + m * 16 + fr) * 64 + pslot];
#pragma unroll
        for (int n = 0; n < 4; ++n)
            b[n] = *(const i32x4*)&ldsB[cur][(wn * 64 + n * 16 + fr) * 64 + pslot];
#pragma unroll
        for (int m = 0; m < 4; ++m)
#pragma unroll
            for (int n = 0; n < 4; ++n)
                acc[m][n] = __builtin_amdgcn_mfma_i32_16x16x64_i8(
                    a[m], b[n], acc[m][n], 0, 0, 0);
        block_bar();  // reads done before next iter overwrites this buffer
    }
#undef STAGE

    // Epilogue: dequant -> weighted exp -> row sums -> atomicAdd.
    // C/D layout: col = lane&15, row = (lane>>4)*4 + j (dtype-independent)
    float lw[4];
    int gc[4];
#pragma unroll
    for (int n = 0; n < 4; ++n) {
        gc[n] = col0 + wn * 64 + n * 16 + fr;
        lw[n] = logw[gc[n]];
    }
    const int rgrp = grp * 4;
#pragma unroll
    for (int m = 0; m < 4; ++m) {
        const int grbase = row0 + wm * 64 + m * 16 + rgrp;
        float rsum[4] = {0.f, 0.f, 0.f, 0.f};
#pragma unroll
        for (int n = 0; n < 4; ++n) {
#pragma unroll
            for (int j = 0; j < 4; ++j) {
                const float logit = (float)acc[m][n][j] * DEQ +
                                    ((gc[n] == grbase + j) ? 0.0f : lw[n]);
                rsum[j] += __expf(logit);
            }
        }
#pragma unroll
        for (int j = 0; j < 4; ++j) {
            float v = rsum[j];
            v += __shfl_xor(v, 1);
            v += __shfl_xor(v, 2);
            v += __shfl_xor(v, 4);
            v += __shfl_xor(v, 8);
            if (fr == 0) atomicAdd(&lsum[grbase + j], v);
        }
    }
}

// Single block: final scalar reduction.
__global__ __launch_bounds__(256) void finalize_kernel(
    const float* __restrict__ lsum, const float* __restrict__ diag,
    const int* __restrict__ labels, float* __restrict__ out) {
    const int tid = threadIdx.x;
    float sl = 0.f, sd = 0.f, mx = -1e9f;
    int np_ = 0, nn_ = 0;
    for (int i = tid; i < NROWS; i += 256) {
        const float dg = diag[i];
        if (labels[i] == 1) {
            sl += logf(lsum[i]) - dg;
            sd += dg;
            np_++;
        } else {
            nn_++;
            mx = fmaxf(mx, dg);
        }
    }
    for (int m = 1; m < 64; m <<= 1) {
        sl += __shfl_xor(sl, m);
        sd += __shfl_xor(sd, m);
        mx = fmaxf(mx, __shfl_xor(mx, m));
        np_ += __shfl_xor(np_, m);
        nn_ += __shfl_xor(nn_, m);
    }
    __shared__ float rsl[4], rsd[4], rmx[4];
    __shared__ int rnp[4], rnn[4];
    const int wave = tid >> 6, lane = tid & 63;
    if (lane == 0) {
        rsl[wave] = sl; rsd[wave] = sd; rmx[wave] = mx;
        rnp[wave] = np_; rnn[wave] = nn_;
    }
    __syncthreads();
    if (tid == 0) {
        float SL = 0.f, SD = 0.f, MX = -1e9f;
        int NP = 0, NN = 0;
        for (int w = 0; w < 4; w++) {
            SL += rsl[w]; SD += rsd[w]; MX = fmaxf(MX, rmx[w]);
            NP += rnp[w]; NN += rnn[w];
        }
        const float infonce = SL / (float)NP;
        const float meanpos = SD / (float)NP;
        float pen = fmaxf(MX - meanpos + 0.2f, 0.0f);
        if (NN == 0) pen = 0.0f;
        out[0] = infonce + pen;
    }
}

extern "C" void kernel_launch(void* const* d_in, const int* in_sizes, int n_in,
                              void* d_out, int out_size, void* d_ws, size_t ws_size,
                              hipStream_t stream) {
    const float* A = (const float*)d_in[0];
    const float* S = (const float*)d_in[1];
    const int* labels = (const int*)d_in[2];
    float* out = (float*)d_out;

    char* ws = (char*)d_ws;
    signed char* aQ = (signed char*)ws;                          // 4 MB
    signed char* sQ = (signed char*)(ws + (size_t)NROWS * DIM);  // 4 MB
    char* p = ws + (size_t)NROWS * DIM * 2;
    float* diag = (float*)p;                // 32 KB
    float* logw = (float*)(p + 32768);      // 32 KB
    float* lsum = (float*)(p + 65536);      // 32 KB

    norm_kernel<<<NROWS / 4, 256, 0, stream>>>(A, S, labels, aQ, sQ, diag, logw, lsum);
    lse_gemm<<<(NROWS / BM) * (NROWS / BN), 256, 0, stream>>>(aQ, sQ, logw, lsum);
    finalize_kernel<<<1, 256, 0, stream>>>(lsum, diag, labels, out);
}

// Round 4
// 67.132 us; speedup vs baseline: 2.4175x; 1.9673x over previous
//
#include <hip/hip_runtime.h>
#include <math.h>

#define NROWS 8192
#define DIM 512
#define INV_T 20.0f
#define LOG_NEG_W 0.69314718055994531f
#define QS 500.0f
#define DEQ (INV_T / (QS * QS))

typedef __attribute__((ext_vector_type(4))) int i32x4;

__device__ __forceinline__ void gload_lds16(const void* g, void* l) {
    __builtin_amdgcn_global_load_lds(
        (const __attribute__((address_space(1))) unsigned int*)g,
        (__attribute__((address_space(3))) unsigned int*)l, 16, 0, 0);
}

__device__ __forceinline__ void block_bar() {
    asm volatile("" ::: "memory");
    __builtin_amdgcn_s_barrier();
    asm volatile("" ::: "memory");
}

__device__ __forceinline__ float dot4(float4 a, float4 b) {
    return a.x * b.x + a.y * b.y + a.z * b.z + a.w * b.w;
}

__device__ __forceinline__ int q4(float4 v, float s) {
    int b0 = __float2int_rn(fminf(fmaxf(v.x * s, -127.f), 127.f)) & 255;
    int b1 = __float2int_rn(fminf(fmaxf(v.y * s, -127.f), 127.f)) & 255;
    int b2 = __float2int_rn(fminf(fmaxf(v.z * s, -127.f), 127.f)) & 255;
    int b3 = __float2int_rn(fminf(fmaxf(v.w * s, -127.f), 127.f)) & 255;
    return b0 | (b1 << 8) | (b2 << 16) | (b3 << 24);
}

// One wave per row: L2-normalize, quantize to i8 (scale QS), exact fp32 diag,
// column log-weights, zero row-sum accumulator.
__global__ __launch_bounds__(256) void norm_kernel(
    const float* __restrict__ A, const float* __restrict__ S,
    const int* __restrict__ labels, signed char* __restrict__ aQ,
    signed char* __restrict__ sQ, float* __restrict__ diag,
    float* __restrict__ logw, float* __restrict__ lsum) {
    const int wave = threadIdx.x >> 6, lane = threadIdx.x & 63;
    const int row = blockIdx.x * 4 + wave;
    const float4* a4 = (const float4*)(A + (size_t)row * DIM);
    const float4* s4 = (const float4*)(S + (size_t)row * DIM);
    float4 a0 = a4[lane], a1 = a4[lane + 64];
    float4 s0 = s4[lane], s1 = s4[lane + 64];
    float saa = dot4(a0, a0) + dot4(a1, a1);
    float sss = dot4(s0, s0) + dot4(s1, s1);
    float sas = dot4(a0, s0) + dot4(a1, s1);
    for (int m = 1; m < 64; m <<= 1) {
        saa += __shfl_xor(saa, m);
        sss += __shfl_xor(sss, m);
        sas += __shfl_xor(sas, m);
    }
    const float ra = rsqrtf(saa), rs = rsqrtf(sss);
    signed char* arow = aQ + (size_t)row * DIM;
    signed char* srow = sQ + (size_t)row * DIM;
    *(int*)(arow + lane * 4)       = q4(a0, ra * QS);
    *(int*)(arow + 256 + lane * 4) = q4(a1, ra * QS);
    *(int*)(srow + lane * 4)       = q4(s0, rs * QS);
    *(int*)(srow + 256 + lane * 4) = q4(s1, rs * QS);
    if (lane == 0) {
        diag[row] = sas * ra * rs * INV_T;
        logw[row] = (labels[row] == 0) ? LOG_NEG_W : 0.0f;
        lsum[row] = 0.0f;
    }
}

// ---------------------------------------------------------------------------
// Persistent-A-panel fused i8 GEMM + exp + row-sum.
// Block = 128 rows x 512 cols (4 column-tiles of 128), 4 waves (2x2).
// A panel 128x512 i8 (64 KB) staged ONCE, swizzled (slot ^= row&31).
// B double-buffered (2x8 KB), 1-deep prefetch, counted vmcnt(2).
// 32 k-iterations per block; 2 blocks/CU (80 KB LDS).
// ---------------------------------------------------------------------------
#define BM 128

__global__ __launch_bounds__(256) void lse_gemm(
    const signed char* __restrict__ Aq, const signed char* __restrict__ Bq,
    const float* __restrict__ logw, float* __restrict__ lsum) {
    __shared__ __align__(16) char ldsA[BM * 512];    // 64 KB, full K panel
    __shared__ __align__(16) char ldsB[2][128 * 64]; // 16 KB dbuf

    const int bid = blockIdx.x;            // 1024 blocks
    const int rt = bid & 63, ctg = bid >> 6;  // rt consecutive -> XCD round-robin
    const int row0 = rt * BM;
    const int colg = ctg * 512;

    const int tid = threadIdx.x;
    const int wave = tid >> 6, lane = tid & 63;
    const int wm = wave >> 1, wn = wave & 1;
    const int fr = lane & 15, grp = lane >> 4;
    const int wbase = wave << 10;  // wave-uniform LDS dest offset

    // ---- A panel staging: 16 rounds x 8 rows. Thread t lands at byte
    // r*4096 + t*16 -> row = r*8 + (t>>5), phys slot = t&31. Fetch logical
    // slot (t&31) ^ (row&31) so swizzled reads see linear data (involution).
#pragma unroll
    for (int r = 0; r < 16; ++r) {
        const int rowA = r * 8 + (tid >> 5);
        const int l = (tid & 31) ^ (rowA & 31);
        gload_lds16(Aq + (size_t)(row0 + rowA) * DIM + l * 16,
                    ldsA + r * 4096 + wbase);
    }

    // B staging coords (r3-verified): thread fills phys slot (tid&3) of row
    // (tid>>2) (+64 for second half); fetches logical slot ^((row>>1)&3).
    const int srowB = tid >> 2;
    const int slB = (tid & 3) ^ ((srowB >> 1) & 3);

#define STAGE_B(buf, ct, k)                                                     \
    do {                                                                        \
        const size_t bb = (size_t)(colg + (ct) * 128 + srowB) * DIM +           \
                          (k) * 64 + slB * 16;                                  \
        gload_lds16(Bq + bb, ldsB[buf] + wbase);                                \
        gload_lds16(Bq + bb + 64 * DIM, ldsB[buf] + 4096 + wbase);              \
    } while (0)

    STAGE_B(0, 0, 0);

    // fragment-read constants
    const int bslot = (grp ^ ((fr >> 1) & 3)) << 4;  // B phys slot byte off

    float rsum[4][4] = {};  // [m][j] accumulated across all 4 ct
    float lwv[4];
    int gc[4];

    for (int ct = 0; ct < 4; ++ct) {
        i32x4 acc[4][4] = {};
#pragma unroll
        for (int k = 0; k < 8; ++k) {
            const int cur = k & 1;
            // A fragment reads: independent of B staging -> overlap the wait
            i32x4 a[4];
#pragma unroll
            for (int m = 0; m < 4; ++m) {
                const int row = wm * 64 + m * 16 + fr;
                const int ps = ((k * 4 + grp) ^ (row & 31)) << 4;
                a[m] = *(const i32x4*)&ldsA[row * 512 + ps];
            }
            if (k < 7) {
                STAGE_B(cur ^ 1, ct, k + 1);
                asm volatile("s_waitcnt vmcnt(2)" ::: "memory");
            } else if (ct < 3) {
                STAGE_B(cur ^ 1, ct + 1, 0);
                asm volatile("s_waitcnt vmcnt(2)" ::: "memory");
            } else {
                asm volatile("s_waitcnt vmcnt(0)" ::: "memory");
            }
            block_bar();  // everyone's B(cur) staged

            i32x4 b[4];
#pragma unroll
            for (int n = 0; n < 4; ++n)
                b[n] = *(const i32x4*)&ldsB[cur][(wn * 64 + n * 16 + fr) * 64 + bslot];
#pragma unroll
            for (int m = 0; m < 4; ++m)
#pragma unroll
                for (int n = 0; n < 4; ++n)
                    acc[m][n] = __builtin_amdgcn_mfma_i32_16x16x64_i8(
                        a[m], b[n], acc[m][n], 0, 0, 0);
            block_bar();  // B(cur) reads done before it is overwritten
        }

        // per-ct epilogue: dequant -> weighted exp -> accumulate rsum
        const int col0 = colg + ct * 128;
#pragma unroll
        for (int n = 0; n < 4; ++n) {
            gc[n] = col0 + wn * 64 + n * 16 + fr;
            lwv[n] = logw[gc[n]];
        }
#pragma unroll
        for (int m = 0; m < 4; ++m) {
            const int grbase = row0 + wm * 64 + m * 16 + grp * 4;
#pragma unroll
            for (int n = 0; n < 4; ++n)
#pragma unroll
                for (int j = 0; j < 4; ++j) {
                    const float logit = (float)acc[m][n][j] * DEQ +
                                        ((gc[n] == grbase + j) ? 0.0f : lwv[n]);
                    rsum[m][j] += __expf(logit);
                }
        }
    }
#undef STAGE_B

    // final: reduce rsum over the 16-lane fr group, one atomicAdd per row
#pragma unroll
    for (int m = 0; m < 4; ++m)
#pragma unroll
        for (int j = 0; j < 4; ++j) {
            float v = rsum[m][j];
            v += __shfl_xor(v, 1);
            v += __shfl_xor(v, 2);
            v += __shfl_xor(v, 4);
            v += __shfl_xor(v, 8);
            if (fr == 0)
                atomicAdd(&lsum[row0 + wm * 64 + m * 16 + grp * 4 + j], v);
        }
}

// 1024 threads, single block: final scalar reduction.
__global__ __launch_bounds__(1024) void finalize_kernel(
    const float* __restrict__ lsum, const float* __restrict__ diag,
    const int* __restrict__ labels, float* __restrict__ out) {
    const int tid = threadIdx.x;
    float sl = 0.f, sd = 0.f, mx = -1e9f;
    int np_ = 0, nn_ = 0;
#pragma unroll
    for (int i = tid; i < NROWS; i += 1024) {
        const float dg = diag[i];
        if (labels[i] == 1) {
            sl += logf(lsum[i]) - dg;
            sd += dg;
            np_++;
        } else {
            nn_++;
            mx = fmaxf(mx, dg);
        }
    }
    for (int m = 1; m < 64; m <<= 1) {
        sl += __shfl_xor(sl, m);
        sd += __shfl_xor(sd, m);
        mx = fmaxf(mx, __shfl_xor(mx, m));
        np_ += __shfl_xor(np_, m);
        nn_ += __shfl_xor(nn_, m);
    }
    __shared__ float rsl[16], rsd[16], rmx[16];
    __shared__ int rnp[16], rnn[16];
    const int wave = tid >> 6, lane = tid & 63;
    if (lane == 0) {
        rsl[wave] = sl; rsd[wave] = sd; rmx[wave] = mx;
        rnp[wave] = np_; rnn[wave] = nn_;
    }
    __syncthreads();
    if (tid == 0) {
        float SL = 0.f, SD = 0.f, MX = -1e9f;
        int NP = 0, NN = 0;
        for (int w = 0; w < 16; w++) {
            SL += rsl[w]; SD += rsd[w]; MX = fmaxf(MX, rmx[w]);
            NP += rnp[w]; NN += rnn[w];
        }
        const float infonce = SL / (float)NP;
        const float meanpos = SD / (float)NP;
        float pen = fmaxf(MX - meanpos + 0.2f, 0.0f);
        if (NN == 0) pen = 0.0f;
        out[0] = infonce + pen;
    }
}

extern "C" void kernel_launch(void* const* d_in, const int* in_sizes, int n_in,
                              void* d_out, int out_size, void* d_ws, size_t ws_size,
                              hipStream_t stream) {
    const float* A = (const float*)d_in[0];
    const float* S = (const float*)d_in[1];
    const int* labels = (const int*)d_in[2];
    float* out = (float*)d_out;

    char* ws = (char*)d_ws;
    signed char* aQ = (signed char*)ws;                          // 4 MB
    signed char* sQ = (signed char*)(ws + (size_t)NROWS * DIM);  // 4 MB
    char* p = ws + (size_t)NROWS * DIM * 2;
    float* diag = (float*)p;                // 32 KB
    float* logw = (float*)(p + 32768);      // 32 KB
    float* lsum = (float*)(p + 65536);      // 32 KB

    norm_kernel<<<NROWS / 4, 256, 0, stream>>>(A, S, labels, aQ, sQ, diag, logw, lsum);
    lse_gemm<<<64 * 16, 256, 0, stream>>>(aQ, sQ, logw, lsum);
    finalize_kernel<<<1, 1024, 0, stream>>>(lsum, diag, labels, out);
}